// Round 1
// baseline (16816.959 us; speedup 1.0000x reference)
//
#include <hip/hip_runtime.h>

// LSTM decoder: B=64, S=512, D=512, H=512, L=2.
// Round 1: fp32 correctness baseline.
//   - one launch per timestep carrying {layer0(t), layer1(t-1)} in disjoint block halves
//   - ping-pong h buffers in ws; element-wise in-place c update
//   - GEMV core: LDS-staged activations (transposed, pitch 66 -> conflict-free float2 reads),
//     weights via wave-uniform scalar loads (readfirstlane-forced)
// ws usage: 196608 floats = 768 KB.

#define NB 64
#define NS 512
#define ND 512
#define NH 512
#define NG 2048   // 4*H

#define UPB 2     // units per block (grid: 256 blocks per layer-role)
#define THREADS 256

struct CellArgs {
    const float* x;   unsigned long long xbs;  // activation input, batch stride
    const float* hp;                            // previous h [B][H]
    float* c;                                   // cell state [B][H] (in-place)
    float* ho;                                  // new h output [B][H]
    const float* wih; const float* whh;         // [4H][512] each
    const float* bih; const float* bhh;         // [4H]
    float* outp;      unsigned long long obs;   // optional out slice (layer1), batch stride
    int active;
};

__global__ void init_state_k(const float* __restrict__ eh, const float* __restrict__ ec,
                             float* __restrict__ ws) {
    int i = blockIdx.x * blockDim.x + threadIdx.x;
    if (i < NB * NH) {
        float h = eh[i], c = ec[i];
        ws[i]          = h;   // h0 buf 0
        ws[65536 + i]  = h;   // h1 buf 0
        ws[131072 + i] = c;   // c0
        ws[163840 + i] = c;   // c1
    }
}

__global__ void final_copy_k(const float* __restrict__ h, const float* __restrict__ c,
                             float* __restrict__ dst) {
    int i = blockIdx.x * blockDim.x + threadIdx.x;
    if (i < NB * NH) {
        dst[i] = h[i];
        dst[NB * NH + i] = c[i];
    }
}

// Accumulate acc[0..1] += xsrc[b,:] . W[r0,:] and W[r0+1,:]  over K=512.
__device__ __forceinline__ void accum_part(const float* __restrict__ xsrc,
                                           unsigned long long xbs,
                                           const float* __restrict__ wl, int r0,
                                           float (*As)[66], float* acc, int tid) {
    const int lane = tid & 63;       // batch index for compute; k index for staging
    const int bq   = tid >> 6;
    const float* __restrict__ w0 = wl + (unsigned long long)r0 * 512ull;
    const float* __restrict__ w1 = w0 + 512ull;

    for (int k0 = 0; k0 < 512; k0 += 64) {
        __syncthreads();
        // stage chunk transposed: As[b][kk] = x[b][k0+kk]; lanes sweep kk -> coalesced
        #pragma unroll
        for (int j = 0; j < 16; ++j) {
            int b = bq + (j << 2);
            As[b][lane] = xsrc[(unsigned long long)b * xbs + (unsigned long long)(k0 + lane)];
        }
        __syncthreads();
        #pragma unroll
        for (int k = 0; k < 64; k += 2) {
            float2 a2 = *(const float2*)(&As[lane][k]);   // own batch row, 2-way bank alias (free)
            float s00 = w0[k0 + k], s01 = w0[k0 + k + 1]; // scalar (SGPR) loads
            float s10 = w1[k0 + k], s11 = w1[k0 + k + 1];
            acc[0] = fmaf(a2.x, s00, acc[0]);
            acc[0] = fmaf(a2.y, s01, acc[0]);
            acc[1] = fmaf(a2.x, s10, acc[1]);
            acc[1] = fmaf(a2.y, s11, acc[1]);
        }
    }
}

__global__ __launch_bounds__(THREADS)
void lstm_step_k(CellArgs a0, CellArgs a1) {
    __shared__ float As[NB][66];
    __shared__ float Gs[4][UPB][NB];

    const bool role0 = (blockIdx.x < 256);
    const CellArgs a = role0 ? a0 : a1;   // block-uniform select
    if (!a.active) return;

    const int tid  = threadIdx.x;
    const int lane = tid & 63;            // batch b
    const int q    = tid >> 6;            // gate index 0..3 (wave-uniform)
    const int qu   = __builtin_amdgcn_readfirstlane(q);
    const int u0   = (blockIdx.x & 255) * UPB;

    float acc[UPB] = {0.f, 0.f};
    const int r0 = qu * NH + u0;          // W row for (gate qu, unit u0); r0+1 = next unit

    accum_part(a.x,  a.xbs, a.wih, r0, As, acc, tid);
    accum_part(a.hp, NH,    a.whh, r0, As, acc, tid);

    // biases, publish gates to LDS
    float b0 = a.bih[r0]     + a.bhh[r0];
    float b1 = a.bih[r0 + 1] + a.bhh[r0 + 1];
    Gs[qu][0][lane] = acc[0] + b0;
    Gs[qu][1][lane] = acc[1] + b1;
    __syncthreads();

    // cell update: threads with q < UPB each own one unit (u = q)
    if (q < UPB) {
        int ug = u0 + q;
        float gi = Gs[0][q][lane];
        float gf = Gs[1][q][lane];
        float gg = Gs[2][q][lane];
        float go = Gs[3][q][lane];
        float ii = 1.f / (1.f + expf(-gi));
        float ff = 1.f / (1.f + expf(-gf));
        float g  = tanhf(gg);
        float oo = 1.f / (1.f + expf(-go));
        unsigned long long off = (unsigned long long)lane * NH + (unsigned long long)ug;
        float cn = ff * a.c[off] + ii * g;
        float hn = oo * tanhf(cn);
        a.c[off]  = cn;
        a.ho[off] = hn;
        if (a.outp) a.outp[(unsigned long long)lane * a.obs + (unsigned long long)ug] = hn;
    }
}

extern "C" void kernel_launch(void* const* d_in, const int* in_sizes, int n_in,
                              void* d_out, int out_size, void* d_ws, size_t ws_size,
                              hipStream_t stream) {
    const float* input = (const float*)d_in[0];
    const float* enc_h = (const float*)d_in[1];
    const float* enc_c = (const float*)d_in[2];
    const float* W_ih  = (const float*)d_in[3];
    const float* W_hh  = (const float*)d_in[4];
    const float* b_ih  = (const float*)d_in[5];
    const float* b_hh  = (const float*)d_in[6];
    float* out = (float*)d_out;
    float* ws  = (float*)d_ws;

    float* h0b[2] = { ws,          ws + 32768 };
    float* h1b[2] = { ws + 65536,  ws + 98304 };
    float* c0 = ws + 131072;
    float* c1 = ws + 163840;

    init_state_k<<<(NB * NH + 255) / 256, 256, 0, stream>>>(enc_h, enc_c, ws);

    // launch t carries {layer0 step t, layer1 step t-1} (pipelined; L1(t-1) only needs h0(t-1))
    for (int t = 0; t <= NS; ++t) {
        CellArgs a0 = {};
        CellArgs a1 = {};

        a0.active = (t < NS) ? 1 : 0;
        if (a0.active) {
            a0.x   = input + (unsigned long long)t * ND;
            a0.xbs = (unsigned long long)NS * ND;
            a0.hp  = h0b[t & 1];
            a0.c   = c0;
            a0.ho  = h0b[(t + 1) & 1];
            a0.wih = W_ih;  a0.whh = W_hh;
            a0.bih = b_ih;  a0.bhh = b_hh;
            a0.outp = nullptr; a0.obs = 0;
        }

        int s = t - 1;
        a1.active = (s >= 0) ? 1 : 0;
        if (a1.active) {
            a1.x   = h0b[(s + 1) & 1];   // h0 produced for step s (last launch)
            a1.xbs = NH;
            a1.hp  = h1b[s & 1];
            a1.c   = c1;
            a1.ho  = h1b[(s + 1) & 1];
            a1.wih = W_ih + (unsigned long long)NG * ND;
            a1.whh = W_hh + (unsigned long long)NG * NH;
            a1.bih = b_ih + NG;  a1.bhh = b_hh + NG;
            a1.outp = out + (unsigned long long)s * NH;
            a1.obs  = (unsigned long long)NS * NH;
        }

        lstm_step_k<<<512, THREADS, 0, stream>>>(a0, a1);
    }

    // tail of d_out: hs[-1] = final h1, cs[-1] = final c1.
    // last L1 write was s=511 -> h1b[(511+1)&1] = h1b[0].
    final_copy_k<<<(NB * NH + 255) / 256, 256, 0, stream>>>(
        h1b[0], c1, out + (unsigned long long)NB * NS * NH);
}

// Round 2
// 3279.469 us; speedup vs baseline: 5.1280x; 5.1280x over previous
//
#include <hip/hip_runtime.h>

// LSTM decoder B=64,S=512,D=512,H=512,L=2 — Round 2: bf16 MFMA per-step GEMM.
// Per launch: role0 = layer0 step t, role1 = layer1 step t-1 (pipelined).
// Weights pre-packed once per call into MFMA B-fragment order (bf16) in ws.
// Per block: 16 batches x 16 units x 4 gates, K=1024 (x|h concat).
//   wave g (=gate) : C[16,16] = 32 x mfma_f32_16x16x32_bf16
//   A staged fragment-packed in LDS (lane-linear ds_read_b128, conflict-free)
//   B fragments loaded straight from global (1 coalesced dwordx4 each)

#define NB 64
#define NS 512
#define ND 512
#define NH 512

typedef __attribute__((ext_vector_type(8))) short short8;
typedef __attribute__((ext_vector_type(4))) float f32x4;

// ---- ws layout (bytes) ----
// 0        : Wpk   2 roles * 128nt * 32k0i * 512 bf16 = 8,388,608
// 8388608  : bias  2*2048 fp32 = 16384
// 8404992  : h0b[0] bf16 64*512 = 65536
// 8470528  : h0b[1]
// 8536064  : h1b[0]
// 8601600  : h1b[1]
// 8667136  : c0 fp32 = 131072
// 8798208  : c1 fp32 = 131072
#define WPK_ELEMS_PER_ROLE (128 * 32 * 512)
#define BIAS_OFF   8388608
#define H0B0_OFF   8404992
#define H0B1_OFF   8470528
#define H1B0_OFF   8536064
#define H1B1_OFF   8601600
#define C0_OFF     8667136
#define C1_OFF     8798208

__device__ __forceinline__ unsigned int pack2bf(float a, float b) {
    unsigned int ua = __builtin_bit_cast(unsigned int, a);
    unsigned int ub = __builtin_bit_cast(unsigned int, b);
    ua += 0x7fffu + ((ua >> 16) & 1u);   // RNE
    ub += 0x7fffu + ((ub >> 16) & 1u);
    return (ua >> 16) | (ub & 0xffff0000u);
}
__device__ __forceinline__ unsigned short bf16r(float a) {
    unsigned int ua = __builtin_bit_cast(unsigned int, a);
    ua += 0x7fffu + ((ua >> 16) & 1u);
    return (unsigned short)(ua >> 16);
}

// Repack weights: fragment (r, nt, k0i) holds lane l, elem j:
//   B[k][n] = W[r][n][k'] with n = nt*16 + (l&15), k = k0i*32 + (l>>4)*8 + j
//   k < 512 -> W_ih[r][n][k], else W_hh[r][n][k-512]
__global__ void prep_weights_k(const float* __restrict__ W_ih,
                               const float* __restrict__ W_hh,
                               unsigned int* __restrict__ wpk_u32) {
    long long gid = (long long)blockIdx.x * blockDim.x + threadIdx.x; // 524288
    int l   = (int)(gid & 63);
    int k0i = (int)((gid >> 6) & 31);
    int nt  = (int)((gid >> 11) & 127);
    int r   = (int)(gid >> 18);
    int n = nt * 16 + (l & 15);
    int k = k0i * 32 + ((l >> 4) << 3);
    const float* src;
    if (k < 512) src = W_ih + ((long long)r * 2048 + n) * 512 + k;
    else         src = W_hh + ((long long)r * 2048 + n) * 512 + (k - 512);
    uint4 v;
    v.x = pack2bf(src[0], src[1]);
    v.y = pack2bf(src[2], src[3]);
    v.z = pack2bf(src[4], src[5]);
    v.w = pack2bf(src[6], src[7]);
    ((uint4*)wpk_u32)[gid] = v;
}

__global__ void prep_state_k(const float* __restrict__ eh, const float* __restrict__ ec,
                             const float* __restrict__ b_ih, const float* __restrict__ b_hh,
                             unsigned char* __restrict__ ws) {
    int i = blockIdx.x * blockDim.x + threadIdx.x;  // 32768 threads
    if (i < NB * NH) {
        float h = eh[i], c = ec[i];
        unsigned short hb = bf16r(h);
        ((unsigned short*)(ws + H0B0_OFF))[i] = hb;
        ((unsigned short*)(ws + H1B0_OFF))[i] = hb;
        ((float*)(ws + C0_OFF))[i] = c;
        ((float*)(ws + C1_OFF))[i] = c;
    }
    if (i < 2 * 2048) {
        ((float*)(ws + BIAS_OFF))[i] = b_ih[i] + b_hh[i];
    }
}

struct RoleArgs {
    const void* x;            // activation input rows [64][...]
    long long xbs;            // batch stride in elements
    int x_bf16;               // 0: fp32 (convert), 1: bf16 (copy)
    const unsigned short* hp; // prev h, bf16 [64][512]
    float* c;                 // cell state fp32 [64][512], in-place
    unsigned short* ho;       // new h, bf16 [64][512]
    const unsigned short* wpk;// role's packed weights
    const float* bias;        // role's combined biases [2048]
    float* outp;              // fp32 out slice (already + s*NH) or null
    int active;
};

__global__ __launch_bounds__(256)
void lstm_step_k(RoleArgs a0, RoleArgs a1) {
    __shared__ alignas(16) unsigned char smem[32768];
    const int bid = blockIdx.x;
    const RoleArgs a = (bid < 128) ? a0 : a1;
    if (!a.active) return;

    const int lb  = bid & 127;
    const int ms  = lb >> 5;        // 0..3  (batch block)
    const int us  = lb & 31;        // 0..31 (unit block)
    const int m0  = ms << 4;
    const int tid = threadIdx.x;
    const int lane = tid & 63;

    // ---- stage A: rows m0..m0+15, K=1024 (x:0..511 | h:512..1023), packed ----
    // chunk k0i*1024B + slot l*16B ; slot l = row m0+(l&15), k = k0i*32+(l>>4)*8
    #pragma unroll
    for (int i = 0; i < 8; ++i) {
        int sid = i * 256 + tid;
        int k0i = sid >> 6;          // wave-uniform per i
        int l   = sid & 63;
        int m   = m0 + (l & 15);
        int kk  = (l >> 4) << 3;     // 0,8,16,24
        uint4 val;
        if (k0i < 16) {
            int k = k0i * 32 + kk;
            if (a.x_bf16) {
                val = *(const uint4*)((const unsigned short*)a.x + (long long)m * a.xbs + k);
            } else {
                const float* s = (const float*)a.x + (long long)m * a.xbs + k;
                val.x = pack2bf(s[0], s[1]);
                val.y = pack2bf(s[2], s[3]);
                val.z = pack2bf(s[4], s[5]);
                val.w = pack2bf(s[6], s[7]);
            }
        } else {
            int k = (k0i - 16) * 32 + kk;
            val = *(const uint4*)(a.hp + (long long)m * 512 + k);
        }
        *(uint4*)(smem + sid * 16) = val;
    }
    __syncthreads();

    // ---- GEMM: wave g = gate; units us*16..+15 ; batches m0..+15 ----
    const int g  = __builtin_amdgcn_readfirstlane(tid >> 6);
    const int nt = g * 32 + us;
    const unsigned short* wp = a.wpk + (long long)nt * (32 * 512);
    f32x4 acc = {0.f, 0.f, 0.f, 0.f};
    #pragma unroll
    for (int k0i = 0; k0i < 32; ++k0i) {
        short8 av = *(const short8*)(smem + k0i * 1024 + lane * 16);
        short8 bv = *(const short8*)(wp + k0i * 512 + lane * 8);
        acc = __builtin_amdgcn_mfma_f32_16x16x32_bf16(av, bv, acc, 0, 0, 0);
    }
    __syncthreads();   // done reading A; reuse smem for gates

    float (*Gs)[16][17] = (float (*)[16][17])smem;
    {
        int u_l  = lane & 15;
        int mrow = (lane >> 4) * 4;
        #pragma unroll
        for (int r = 0; r < 4; ++r)
            Gs[g][mrow + r][u_l] = acc[r];
    }
    __syncthreads();

    // ---- fused LSTM cell: 1 cell per thread ----
    {
        int m_l = tid >> 4;
        int u_l = tid & 15;
        int b   = m0 + m_l;
        int u   = us * 16 + u_l;
        float gi = Gs[0][m_l][u_l] + a.bias[0 * 512 + u];
        float gf = Gs[1][m_l][u_l] + a.bias[1 * 512 + u];
        float gg = Gs[2][m_l][u_l] + a.bias[2 * 512 + u];
        float go = Gs[3][m_l][u_l] + a.bias[3 * 512 + u];
        float ii = 1.f / (1.f + expf(-gi));
        float ff = 1.f / (1.f + expf(-gf));
        float gv = tanhf(gg);
        float oo = 1.f / (1.f + expf(-go));
        long long off = (long long)b * 512 + u;
        float cn = ff * a.c[off] + ii * gv;
        float hn = oo * tanhf(cn);
        a.c[off]  = cn;
        a.ho[off] = bf16r(hn);
        if (a.outp) a.outp[(long long)b * (NS * NH) + u] = hn;
    }
}

__global__ void final_copy_k(const float* __restrict__ out_src,
                             const float* __restrict__ c1,
                             float* __restrict__ dst) {
    int i = blockIdx.x * blockDim.x + threadIdx.x;
    if (i < NB * NH) {
        int b = i >> 9, u = i & 511;
        dst[i] = out_src[(long long)b * (NS * NH) + 511 * NH + u];
        dst[NB * NH + i] = c1[i];
    }
}

extern "C" void kernel_launch(void* const* d_in, const int* in_sizes, int n_in,
                              void* d_out, int out_size, void* d_ws, size_t ws_size,
                              hipStream_t stream) {
    const float* input = (const float*)d_in[0];
    const float* enc_h = (const float*)d_in[1];
    const float* enc_c = (const float*)d_in[2];
    const float* W_ih  = (const float*)d_in[3];
    const float* W_hh  = (const float*)d_in[4];
    const float* b_ih  = (const float*)d_in[5];
    const float* b_hh  = (const float*)d_in[6];
    float* out = (float*)d_out;
    unsigned char* ws = (unsigned char*)d_ws;

    unsigned short* wpk  = (unsigned short*)ws;
    float* bias          = (float*)(ws + BIAS_OFF);
    unsigned short* h0b[2] = { (unsigned short*)(ws + H0B0_OFF), (unsigned short*)(ws + H0B1_OFF) };
    unsigned short* h1b[2] = { (unsigned short*)(ws + H1B0_OFF), (unsigned short*)(ws + H1B1_OFF) };
    float* c0 = (float*)(ws + C0_OFF);
    float* c1 = (float*)(ws + C1_OFF);

    prep_weights_k<<<2048, 256, 0, stream>>>(W_ih, W_hh, (unsigned int*)wpk);
    prep_state_k<<<128, 256, 0, stream>>>(enc_h, enc_c, b_ih, b_hh, ws);

    for (int t = 0; t <= NS; ++t) {
        RoleArgs a0 = {};
        RoleArgs a1 = {};

        a0.active = (t < NS) ? 1 : 0;
        if (a0.active) {
            a0.x      = input + (long long)t * ND;
            a0.xbs    = (long long)NS * ND;
            a0.x_bf16 = 0;
            a0.hp     = h0b[t & 1];
            a0.c      = c0;
            a0.ho     = h0b[(t + 1) & 1];
            a0.wpk    = wpk;
            a0.bias   = bias;
            a0.outp   = nullptr;
        }

        int s = t - 1;
        a1.active = (s >= 0) ? 1 : 0;
        if (a1.active) {
            a1.x      = h0b[t & 1];          // h0 produced for step s (prev launch)
            a1.xbs    = 512;
            a1.x_bf16 = 1;
            a1.hp     = h1b[s & 1];
            a1.c      = c1;
            a1.ho     = h1b[(s + 1) & 1];
            a1.wpk    = wpk + (long long)WPK_ELEMS_PER_ROLE;
            a1.bias   = bias + 2048;
            a1.outp   = out + (long long)s * NH;
        }

        lstm_step_k<<<256, 256, 0, stream>>>(a0, a1);
    }

    final_copy_k<<<128, 256, 0, stream>>>(out, c1, out + (long long)NB * NS * NH);
}